// Round 6
// baseline (1791.763 us; speedup 1.0000x reference)
//
#include <hip/hip_runtime.h>

typedef __attribute__((ext_vector_type(8))) short short8_t;
typedef __attribute__((ext_vector_type(4))) float f32x4;

#define NROWS_TOTAL 524288
#define MROWS 128
#define HSTRIDE 520   // 512 + 8 pad: 260 dwords == 4 mod 32 -> even bank tiling for b128 reads, 16B aligned rows
#define NTHREADS 1024
#define OSTRIDE 108   // f32 out-staging stride

__device__ __forceinline__ unsigned short f32_to_bf16(float f) {
    union { float f; unsigned int u; } v; v.f = f;
    unsigned int r = v.u + 0x7FFFu + ((v.u >> 16) & 1u);
    return (unsigned short)(r >> 16);
}

// ws layout (bf16, transposed Wt[n][k], zero-padded):
//   W1t [512][128] @ 0        (K 105->128)
//   W2t [512][512] @ 65536
//   W3t [512][512] @ 327680
//   W4t [128][512] @ 589824   (N 100->128)
__global__ void conv_weights(const float* __restrict__ W1, const float* __restrict__ W2,
                             const float* __restrict__ W3, const float* __restrict__ W4,
                             unsigned short* __restrict__ ws) {
    int i = blockIdx.x * 256 + threadIdx.x;
    if (i < 65536) {
        int k = i & 127, n = i >> 7;
        ws[i] = f32_to_bf16(k < 105 ? W1[k * 512 + n] : 0.0f);
    } else if (i < 327680) {
        int j = i - 65536; int k = j & 511, n = j >> 9;
        ws[i] = f32_to_bf16(W2[k * 512 + n]);
    } else if (i < 589824) {
        int j = i - 327680; int k = j & 511, n = j >> 9;
        ws[i] = f32_to_bf16(W3[k * 512 + n]);
    } else if (i < 655360) {
        int j = i - 589824; int k = j & 511, n = j >> 9;
        ws[i] = f32_to_bf16(n < 100 ? W4[k * 100 + n] : 0.0f);
    }
}

__device__ __forceinline__ int clamp_bin(float sc) {
    int b = (int)floorf(sc);
    return b < 0 ? 0 : (b > 15 ? 15 : b);
}

// One MLP layer: 16 waves = 2 row-groups x 8 col-groups. Wave = 64 rows x 64 cols,
// acc[4][4] = 64 AGPR -> <=128 regs/wave -> 4 waves/SIMD.
// B: 2-buffer ping-pong, reload issued AFTER last consumer (no rotation movs),
//    giving a full chunk-period of global-load latency slack.
// A: JIT from LDS; ~130cyc latency hidden by 3 sibling waves per SIMD.
// Bias folded into accumulator init.
template<int KDIM>
__device__ __forceinline__ void mlp_layer(unsigned short* hbuf,
                                          const unsigned short* __restrict__ Wt,
                                          const float* __restrict__ bias,
                                          int lane, int wave) {
    const int lrow = lane & 15;
    const int quad = lane >> 4;
    const int rowg = wave >> 3;        // 0..1: which 64-row half
    const int n0   = (wave & 7) * 64;  // col group
    constexpr int NK = KDIM / 32;

    f32x4 acc[4][4];
    #pragma unroll
    for (int nt = 0; nt < 4; ++nt) {
        float bv = bias[n0 + nt * 16 + lrow];
        f32x4 bi = {bv, bv, bv, bv};
        #pragma unroll
        for (int mt = 0; mt < 4; ++mt) acc[mt][nt] = bi;
    }

    const unsigned short* wbase  = Wt + (n0 + lrow) * KDIM + quad * 8;
    const unsigned short* abase0 = hbuf + (rowg * 64 + lrow) * HSTRIDE + quad * 8;

    short8_t bc[2][4];                 // ping-pong, indices compile-time after unroll
    #pragma unroll
    for (int nt = 0; nt < 4; ++nt)
        bc[0][nt] = *(const short8_t*)(wbase + nt * (16 * KDIM));
    #pragma unroll
    for (int nt = 0; nt < 4; ++nt)
        bc[1][nt] = *(const short8_t*)(wbase + nt * (16 * KDIM) + 32);

    #pragma unroll
    for (int kc = 0; kc < NK; ++kc) {
        const int par = kc & 1;
        short8_t a[4];
        #pragma unroll
        for (int mt = 0; mt < 4; ++mt)
            a[mt] = *(const short8_t*)(abase0 + mt * (16 * HSTRIDE) + kc * 32);
        #pragma unroll
        for (int mt = 0; mt < 4; ++mt)
            #pragma unroll
            for (int nt = 0; nt < 4; ++nt)
                acc[mt][nt] = __builtin_amdgcn_mfma_f32_16x16x32_bf16(a[mt], bc[par][nt], acc[mt][nt], 0, 0, 0);
        if (kc + 2 < NK) {             // refill just-consumed buffer for kc+2
            #pragma unroll
            for (int nt = 0; nt < 4; ++nt)
                bc[par][nt] = *(const short8_t*)(wbase + nt * (16 * KDIM) + (kc + 2) * 32);
        }
    }

    __syncthreads();   // all waves finished reading hbuf for this layer

    // Epilogue: relu (bias already in acc), pair-pack adjacent cols via shfl_xor(1), b32 LDS writes.
    // C/D layout: col = lane&15, row = quad*4 + reg (verified m89/m91).
    const int odd = lane & 1;
    #pragma unroll
    for (int mt = 0; mt < 4; ++mt) {
        #pragma unroll
        for (int ntp = 0; ntp < 2; ++ntp) {
            const int t0 = ntp * 2, t1 = t0 + 1;
            const int col = n0 + t0 * 16 + odd * 16 + (lrow & ~1);
            #pragma unroll
            for (int reg = 0; reg < 4; ++reg) {
                float vA = fmaxf(acc[mt][t0][reg], 0.f);
                float vB = fmaxf(acc[mt][t1][reg], 0.f);
                float vm = odd ? vB : vA;   // value for my write-tile at my col
                float vs = odd ? vA : vB;   // value my xor-partner needs
                float vr = __shfl_xor(vs, 1, 64);
                unsigned int ha = f32_to_bf16(vm);
                unsigned int hb = f32_to_bf16(vr);
                unsigned int packed = odd ? (hb | (ha << 16)) : (ha | (hb << 16));
                int row = rowg * 64 + mt * 16 + quad * 4 + reg;
                *(unsigned int*)(hbuf + row * HSTRIDE + col) = packed;
            }
        }
    }
    __syncthreads();
}

__global__ void __launch_bounds__(NTHREADS, 4)
pivnet_fused(const float* __restrict__ x,
             const float* __restrict__ minv, const float* __restrict__ maxv,
             const float* __restrict__ pivots, const float* __restrict__ knnd,
             const float* __restrict__ qmean, const float* __restrict__ qstd,
             const float* __restrict__ kmean, const float* __restrict__ kstd,
             const unsigned short* __restrict__ wsw,
             const float* __restrict__ b1, const float* __restrict__ b2,
             const float* __restrict__ b3, const float* __restrict__ b4,
             float* __restrict__ out) {
    __shared__ unsigned short hbuf[MROWS * HSTRIDE];   // 133,120 B -> 1 block/CU, 16 waves

    const int tid  = threadIdx.x;
    const int lane = tid & 63;
    const int wave = tid >> 6;
    const int row0 = blockIdx.x * MROWS;

    // ---------------- feature phase: 8 threads per row, 1 row per octet ----------------
    {
        const int r = tid >> 3;          // 0..127 local row
        const int p = tid & 7;           // col group [p*16, p*16+16)
        const float mn0 = minv[0], mn1 = minv[1], mn2 = minv[2], mn3 = minv[3];
        const float rg0 = maxv[0] - mn0, rg1 = maxv[1] - mn1, rg2 = maxv[2] - mn2, rg3 = maxv[3] - mn3;
        const float cd2 = (rg0 * rg0 + rg1 * rg1 + rg2 * rg2 + rg3 * rg3) * (1.0f / 256.0f);
        const float4 xr = ((const float4*)x)[row0 + r];
        const float xa0 = xr.x, xa1 = xr.y, xa2 = xr.z, xa3 = xr.w;
        int bidx;
        bidx = clamp_bin((xa0 - mn0) / rg0 * 16.f);
        bidx = bidx * 16 + clamp_bin((xa1 - mn1) / rg1 * 16.f);
        bidx = bidx * 16 + clamp_bin((xa2 - mn2) / rg2 * 16.f);
        bidx = bidx * 16 + clamp_bin((xa3 - mn3) / rg3 * 16.f);
        const float* kr = knnd + (size_t)bidx * 100;

        unsigned short vals[16];
        if (p == 0) {
            vals[0] = f32_to_bf16((xa0 - qmean[0]) / qstd[0]);
            vals[1] = f32_to_bf16((xa1 - qmean[1]) / qstd[1]);
            vals[2] = f32_to_bf16((xa2 - qmean[2]) / qstd[2]);
            vals[3] = f32_to_bf16((xa3 - qmean[3]) / qstd[3]);
            const float4 pv = ((const float4*)pivots)[bidx];
            float d0 = xa0 - pv.x, d1 = xa1 - pv.y, d2 = xa2 - pv.z, d3 = xa3 - pv.w;
            vals[4] = f32_to_bf16(sqrtf((d0 * d0 + d1 * d1 + d2 * d2 + d3 * d3) / cd2));
            #pragma unroll
            for (int j = 5; j < 16; ++j) {
                int k = j - 5;
                vals[j] = f32_to_bf16((kr[k] - kmean[k]) / kstd[k]);
            }
        } else {
            #pragma unroll
            for (int j = 0; j < 16; ++j) {
                int k = p * 16 + j - 5;
                float f = 0.f;
                if (k < 100) f = (kr[k] - kmean[k]) / kstd[k];
                vals[j] = f32_to_bf16(f);
            }
        }
        unsigned int pk[8];
        #pragma unroll
        for (int j = 0; j < 8; ++j)
            pk[j] = (unsigned int)vals[2 * j] | ((unsigned int)vals[2 * j + 1] << 16);
        uint4* d4 = (uint4*)(hbuf + r * HSTRIDE + p * 16);
        d4[0] = make_uint4(pk[0], pk[1], pk[2], pk[3]);
        d4[1] = make_uint4(pk[4], pk[5], pk[6], pk[7]);
    }
    __syncthreads();

    const unsigned short* W1t = wsw;
    const unsigned short* W2t = wsw + 65536;
    const unsigned short* W3t = wsw + 327680;
    const unsigned short* W4t = wsw + 589824;

    mlp_layer<128>(hbuf, W1t, b1, lane, wave);
    mlp_layer<512>(hbuf, W2t, b2, lane, wave);
    mlp_layer<512>(hbuf, W3t, b3, lane, wave);

    // ---------------- layer 4: [128][512] x [512][100->128], stage f32 in LDS, coalesced HBM write ----
    {
        const int lrow = lane & 15;
        const int quad = lane >> 4;
        const int rowg = wave >> 3;              // 0..1
        const int col  = (wave & 7) * 16 + lrow; // 8 col-groups x 16 = 128 padded cols
        f32x4 acc4[4];
        {
            float bv = (col < 100) ? b4[col] : 0.f;
            f32x4 bi = {bv, bv, bv, bv};
            #pragma unroll
            for (int mt = 0; mt < 4; ++mt) acc4[mt] = bi;
        }
        const unsigned short* wb4 = W4t + col * 512 + quad * 8;
        const unsigned short* ab0 = hbuf + (rowg * 64 + lrow) * HSTRIDE + quad * 8;

        short8_t b4c[2];
        b4c[0] = *(const short8_t*)wb4;
        b4c[1] = *(const short8_t*)(wb4 + 32);

        #pragma unroll
        for (int kc = 0; kc < 16; ++kc) {
            const int par = kc & 1;
            short8_t a[4];
            #pragma unroll
            for (int mt = 0; mt < 4; ++mt)
                a[mt] = *(const short8_t*)(ab0 + mt * (16 * HSTRIDE) + kc * 32);
            #pragma unroll
            for (int mt = 0; mt < 4; ++mt)
                acc4[mt] = __builtin_amdgcn_mfma_f32_16x16x32_bf16(a[mt], b4c[par], acc4[mt], 0, 0, 0);
            if (kc + 2 < 16)
                b4c[par] = *(const short8_t*)(wb4 + (kc + 2) * 32);
        }

        __syncthreads();   // all reads of hbuf done; safe to reuse as f32 staging

        float* fstage = (float*)hbuf;
        if (col < 100) {
            #pragma unroll
            for (int mt = 0; mt < 4; ++mt)
                #pragma unroll
                for (int reg = 0; reg < 4; ++reg)
                    fstage[(rowg * 64 + mt * 16 + quad * 4 + reg) * OSTRIDE + col] = acc4[mt][reg];
        }
        __syncthreads();

        // block's out region is one contiguous 128*100*4 = 51200 B span -> float4-coalesced copy
        float* obase = out + (size_t)row0 * 100;
        #pragma unroll
        for (int k = 0; k < 4; ++k) {
            int j = tid + k * 1024;           // float4 index 0..3199
            if (j < 3200) {
                int row = j / 25;             // magic-mul, constant divisor
                int c4  = j - row * 25;
                float4 v = *(const float4*)(fstage + row * OSTRIDE + c4 * 4);
                *(float4*)(obase + 4 * j) = v;
            }
        }
    }
}

extern "C" void kernel_launch(void* const* d_in, const int* in_sizes, int n_in,
                              void* d_out, int out_size, void* d_ws, size_t ws_size,
                              hipStream_t stream) {
    const float* x    = (const float*)d_in[0];
    const float* minv = (const float*)d_in[1];
    const float* maxv = (const float*)d_in[2];
    const float* piv  = (const float*)d_in[3];
    const float* knnd = (const float*)d_in[4];
    const float* qm   = (const float*)d_in[5];
    const float* qs   = (const float*)d_in[6];
    const float* km   = (const float*)d_in[7];
    const float* ks   = (const float*)d_in[8];
    const float* W1   = (const float*)d_in[9];
    const float* b1   = (const float*)d_in[10];
    const float* W2   = (const float*)d_in[11];
    const float* b2   = (const float*)d_in[12];
    const float* W3   = (const float*)d_in[13];
    const float* b3   = (const float*)d_in[14];
    const float* W4   = (const float*)d_in[15];
    const float* b4   = (const float*)d_in[16];
    float* out = (float*)d_out;
    unsigned short* wsw = (unsigned short*)d_ws;   // needs 1,310,720 B

    conv_weights<<<2560, 256, 0, stream>>>(W1, W2, W3, W4, wsw);
    pivnet_fused<<<NROWS_TOTAL / MROWS, NTHREADS, 0, stream>>>(
        x, minv, maxv, piv, knnd, qm, qs, km, ks,
        wsw, b1, b2, b3, b4, out);
}

// Round 7
// 1290.430 us; speedup vs baseline: 1.3885x; 1.3885x over previous
//
#include <hip/hip_runtime.h>

typedef __attribute__((ext_vector_type(8))) short short8_t;
typedef __attribute__((ext_vector_type(16))) float f32x16;

#define NROWS_TOTAL 524288
#define MROWS 128
#define HSTRIDE 536   // 268 dwords == 12 mod 32: 8 consecutive rows hit 8 distinct bank-quads for b128 reads (min aliasing); 16B-aligned rows
#define NTHREADS 512
#define OSTRIDE 108   // f32 out-staging stride (108 % 32 == 12: same conflict-free property)

__device__ __forceinline__ unsigned short f32_to_bf16(float f) {
    union { float f; unsigned int u; } v; v.f = f;
    unsigned int r = v.u + 0x7FFFu + ((v.u >> 16) & 1u);
    return (unsigned short)(r >> 16);
}

// ws layout (bf16, transposed Wt[n][k], zero-padded):
//   W1t [512][128] @ 0        (K 105->128)
//   W2t [512][512] @ 65536
//   W3t [512][512] @ 327680
//   W4t [128][512] @ 589824   (N 100->128)
__global__ void conv_weights(const float* __restrict__ W1, const float* __restrict__ W2,
                             const float* __restrict__ W3, const float* __restrict__ W4,
                             unsigned short* __restrict__ ws) {
    int i = blockIdx.x * 256 + threadIdx.x;
    if (i < 65536) {
        int k = i & 127, n = i >> 7;
        ws[i] = f32_to_bf16(k < 105 ? W1[k * 512 + n] : 0.0f);
    } else if (i < 327680) {
        int j = i - 65536; int k = j & 511, n = j >> 9;
        ws[i] = f32_to_bf16(W2[k * 512 + n]);
    } else if (i < 589824) {
        int j = i - 327680; int k = j & 511, n = j >> 9;
        ws[i] = f32_to_bf16(W3[k * 512 + n]);
    } else if (i < 655360) {
        int j = i - 589824; int k = j & 511, n = j >> 9;
        ws[i] = f32_to_bf16(n < 100 ? W4[k * 100 + n] : 0.0f);
    }
}

__device__ __forceinline__ int clamp_bin(float sc) {
    int b = (int)floorf(sc);
    return b < 0 ? 0 : (b > 15 ? 15 : b);
}

// One MLP layer, 32x32x16 MFMA: 8 waves, wave owns 128 rows x 64 cols
// = 4 mt x 2 nt tiles of 32x32, acc[4][2] x f32x16 = 128 AGPR.
// A operand: row = lane&31, k = (lane>>5)*8 + i  (JIT ds_read per chunk).
// B operand: col = lane&31, k = (lane>>5)*8 + i  (2-buffer parity ping-pong,
//   refilled after last consumer -> no rotation movs, ~2 chunk-periods slack).
// MFMA order: kh-outer -> same-acc dependency distance 8 (~270cyc) > result latency.
// Bias folded into accumulator init. s_setprio(1) wraps the MFMA cluster (T5:
// waves are barrier-free in the K-loop -> phase-diverse -> arbitration helps).
template<int KDIM>
__device__ __forceinline__ void mlp_layer(unsigned short* hbuf,
                                          const unsigned short* __restrict__ Wt,
                                          const float* __restrict__ bias,
                                          int lane, int wave) {
    const int l31 = lane & 31;
    const int lh  = lane >> 5;         // k-half selector
    const int n0  = wave * 64;
    constexpr int NK = KDIM / 32;

    f32x16 acc[4][2];
    #pragma unroll
    for (int nt = 0; nt < 2; ++nt) {
        float bv = bias[n0 + nt * 32 + l31];   // C col = lane&31 -> all 16 regs same col
        #pragma unroll
        for (int mt = 0; mt < 4; ++mt)
            #pragma unroll
            for (int r = 0; r < 16; ++r)
                acc[mt][nt][r] = bv;
    }

    const unsigned short* wbase  = Wt + (n0 + l31) * KDIM + lh * 8;
    const unsigned short* abase0 = hbuf + l31 * HSTRIDE + lh * 8;

    short8_t bc[2][4];   // [parity][nt*2+kh]
    #pragma unroll
    for (int nt = 0; nt < 2; ++nt)
        #pragma unroll
        for (int kh = 0; kh < 2; ++kh) {
            bc[0][nt * 2 + kh] = *(const short8_t*)(wbase + nt * (32 * KDIM) + kh * 16);
            bc[1][nt * 2 + kh] = *(const short8_t*)(wbase + nt * (32 * KDIM) + 32 + kh * 16);
        }

    #pragma unroll
    for (int kc = 0; kc < NK; ++kc) {
        const int par = kc & 1;
        short8_t a[4][2];
        #pragma unroll
        for (int mt = 0; mt < 4; ++mt)
            #pragma unroll
            for (int kh = 0; kh < 2; ++kh)
                a[mt][kh] = *(const short8_t*)(abase0 + mt * (32 * HSTRIDE) + kc * 32 + kh * 16);
        __builtin_amdgcn_s_setprio(1);
        #pragma unroll
        for (int kh = 0; kh < 2; ++kh)
            #pragma unroll
            for (int mt = 0; mt < 4; ++mt)
                #pragma unroll
                for (int nt = 0; nt < 2; ++nt)
                    acc[mt][nt] = __builtin_amdgcn_mfma_f32_32x32x16_bf16(
                        a[mt][kh], bc[par][nt * 2 + kh], acc[mt][nt], 0, 0, 0);
        __builtin_amdgcn_s_setprio(0);
        if (kc + 2 < NK) {   // refill just-consumed parity buffer for chunk kc+2
            #pragma unroll
            for (int nt = 0; nt < 2; ++nt)
                #pragma unroll
                for (int kh = 0; kh < 2; ++kh)
                    bc[par][nt * 2 + kh] =
                        *(const short8_t*)(wbase + nt * (32 * KDIM) + (kc + 2) * 32 + kh * 16);
        }
    }

    __syncthreads();   // all waves finished reading hbuf for this layer

    // Epilogue: relu (bias already in acc), pair-pack adjacent cols via shfl_xor(1), b32 LDS writes.
    // 32x32 C/D layout: col = lane&31, row = (reg&3) + 8*(reg>>2) + 4*(lane>>5)  (verified m74/m101).
    // Even lane writes nt=0 tile, odd lane writes nt=1 tile at the same even col base.
    const int odd = lane & 1;
    const int colw = n0 + odd * 32 + (l31 & ~1);
    #pragma unroll
    for (int mt = 0; mt < 4; ++mt) {
        #pragma unroll
        for (int reg = 0; reg < 16; ++reg) {
            float vA = fmaxf(acc[mt][0][reg], 0.f);
            float vB = fmaxf(acc[mt][1][reg], 0.f);
            float vm = odd ? vB : vA;   // value for my write-tile at my col
            float vs = odd ? vA : vB;   // value my xor-partner needs
            float vr = __shfl_xor(vs, 1, 64);
            unsigned int ha = f32_to_bf16(vm);
            unsigned int hb = f32_to_bf16(vr);
            unsigned int packed = odd ? (hb | (ha << 16)) : (ha | (hb << 16));
            int row = mt * 32 + (reg & 3) + 8 * (reg >> 2) + 4 * lh;
            *(unsigned int*)(hbuf + row * HSTRIDE + colw) = packed;
        }
    }
    __syncthreads();
}

__global__ void __launch_bounds__(NTHREADS, 2)
pivnet_fused(const float* __restrict__ x,
             const float* __restrict__ minv, const float* __restrict__ maxv,
             const float* __restrict__ pivots, const float* __restrict__ knnd,
             const float* __restrict__ qmean, const float* __restrict__ qstd,
             const float* __restrict__ kmean, const float* __restrict__ kstd,
             const unsigned short* __restrict__ wsw,
             const float* __restrict__ b1, const float* __restrict__ b2,
             const float* __restrict__ b3, const float* __restrict__ b4,
             float* __restrict__ out) {
    __shared__ unsigned short hbuf[MROWS * HSTRIDE];   // 137,216 B -> 1 block/CU, 8 waves

    const int tid  = threadIdx.x;
    const int lane = tid & 63;
    const int wave = tid >> 6;
    const int row0 = blockIdx.x * MROWS;

    // ---------------- feature phase: 8 threads per row, 2 rows/thread ----------------
    {
        const int p = tid & 7;           // col group [p*16, p*16+16)
        const float mn0 = minv[0], mn1 = minv[1], mn2 = minv[2], mn3 = minv[3];
        const float rg0 = maxv[0] - mn0, rg1 = maxv[1] - mn1, rg2 = maxv[2] - mn2, rg3 = maxv[3] - mn3;
        const float cd2 = (rg0 * rg0 + rg1 * rg1 + rg2 * rg2 + rg3 * rg3) * (1.0f / 256.0f);
        #pragma unroll
        for (int rep = 0; rep < 2; ++rep) {
            const int r = (tid >> 3) + rep * 64;   // 0..127 local row
            const float4 xr = ((const float4*)x)[row0 + r];
            const float xa0 = xr.x, xa1 = xr.y, xa2 = xr.z, xa3 = xr.w;
            int bidx;
            bidx = clamp_bin((xa0 - mn0) / rg0 * 16.f);
            bidx = bidx * 16 + clamp_bin((xa1 - mn1) / rg1 * 16.f);
            bidx = bidx * 16 + clamp_bin((xa2 - mn2) / rg2 * 16.f);
            bidx = bidx * 16 + clamp_bin((xa3 - mn3) / rg3 * 16.f);
            const float* kr = knnd + (size_t)bidx * 100;

            unsigned short vals[16];
            if (p == 0) {
                vals[0] = f32_to_bf16((xa0 - qmean[0]) / qstd[0]);
                vals[1] = f32_to_bf16((xa1 - qmean[1]) / qstd[1]);
                vals[2] = f32_to_bf16((xa2 - qmean[2]) / qstd[2]);
                vals[3] = f32_to_bf16((xa3 - qmean[3]) / qstd[3]);
                const float4 pv = ((const float4*)pivots)[bidx];
                float d0 = xa0 - pv.x, d1 = xa1 - pv.y, d2 = xa2 - pv.z, d3 = xa3 - pv.w;
                vals[4] = f32_to_bf16(sqrtf((d0 * d0 + d1 * d1 + d2 * d2 + d3 * d3) / cd2));
                #pragma unroll
                for (int j = 5; j < 16; ++j) {
                    int k = j - 5;
                    vals[j] = f32_to_bf16((kr[k] - kmean[k]) / kstd[k]);
                }
            } else {
                #pragma unroll
                for (int j = 0; j < 16; ++j) {
                    int k = p * 16 + j - 5;
                    float f = 0.f;
                    if (k < 100) f = (kr[k] - kmean[k]) / kstd[k];
                    vals[j] = f32_to_bf16(f);
                }
            }
            unsigned int pk[8];
            #pragma unroll
            for (int j = 0; j < 8; ++j)
                pk[j] = (unsigned int)vals[2 * j] | ((unsigned int)vals[2 * j + 1] << 16);
            uint4* d4 = (uint4*)(hbuf + r * HSTRIDE + p * 16);
            d4[0] = make_uint4(pk[0], pk[1], pk[2], pk[3]);
            d4[1] = make_uint4(pk[4], pk[5], pk[6], pk[7]);
        }
    }
    __syncthreads();

    const unsigned short* W1t = wsw;
    const unsigned short* W2t = wsw + 65536;
    const unsigned short* W3t = wsw + 327680;
    const unsigned short* W4t = wsw + 589824;

    mlp_layer<128>(hbuf, W1t, b1, lane, wave);
    mlp_layer<512>(hbuf, W2t, b2, lane, wave);
    mlp_layer<512>(hbuf, W3t, b3, lane, wave);

    // ---------------- layer 4: [128][512] x [512][100->128], 32x32 tiles, f32 LDS staging ----
    {
        const int l31 = lane & 31;
        const int lh  = lane >> 5;
        const int nt4  = wave & 3;          // col tile: cols nt4*32..+31
        const int rowg = wave >> 2;         // 0..1 -> rows rowg*64..+63 (2 mt tiles)
        const int col  = nt4 * 32 + l31;
        f32x16 acc4[2];
        {
            float bv = (col < 100) ? b4[col] : 0.f;
            #pragma unroll
            for (int mt = 0; mt < 2; ++mt)
                #pragma unroll
                for (int r = 0; r < 16; ++r) acc4[mt][r] = bv;
        }
        const unsigned short* wb4 = W4t + col * 512 + lh * 8;
        const unsigned short* ab0 = hbuf + (rowg * 64 + l31) * HSTRIDE + lh * 8;

        short8_t b4c[2][2];   // [parity][kh]
        #pragma unroll
        for (int kh = 0; kh < 2; ++kh) {
            b4c[0][kh] = *(const short8_t*)(wb4 + kh * 16);
            b4c[1][kh] = *(const short8_t*)(wb4 + 32 + kh * 16);
        }

        #pragma unroll
        for (int kc = 0; kc < 16; ++kc) {
            const int par = kc & 1;
            short8_t a[2][2];
            #pragma unroll
            for (int mt = 0; mt < 2; ++mt)
                #pragma unroll
                for (int kh = 0; kh < 2; ++kh)
                    a[mt][kh] = *(const short8_t*)(ab0 + mt * (32 * HSTRIDE) + kc * 32 + kh * 16);
            __builtin_amdgcn_s_setprio(1);
            #pragma unroll
            for (int kh = 0; kh < 2; ++kh)
                #pragma unroll
                for (int mt = 0; mt < 2; ++mt)
                    acc4[mt] = __builtin_amdgcn_mfma_f32_32x32x16_bf16(
                        a[mt][kh], b4c[par][kh], acc4[mt], 0, 0, 0);
            __builtin_amdgcn_s_setprio(0);
            if (kc + 2 < 16) {
                #pragma unroll
                for (int kh = 0; kh < 2; ++kh)
                    b4c[par][kh] = *(const short8_t*)(wb4 + (kc + 2) * 32 + kh * 16);
            }
        }

        __syncthreads();   // all reads of hbuf done; safe to reuse as f32 staging

        float* fstage = (float*)hbuf;
        if (col < 100) {
            #pragma unroll
            for (int mt = 0; mt < 2; ++mt)
                #pragma unroll
                for (int reg = 0; reg < 16; ++reg) {
                    int row = rowg * 64 + mt * 32 + (reg & 3) + 8 * (reg >> 2) + 4 * lh;
                    fstage[row * OSTRIDE + col] = acc4[mt][reg];
                }
        }
        __syncthreads();

        // block's out region is one contiguous 128*100*4 = 51200 B span -> float4-coalesced copy
        float* obase = out + (size_t)row0 * 100;
        #pragma unroll
        for (int k = 0; k < 7; ++k) {
            int j = tid + k * 512;            // float4 index 0..3199
            if (j < 3200) {
                int row = j / 25;             // magic-mul, constant divisor
                int c4  = j - row * 25;
                float4 v = *(const float4*)(fstage + row * OSTRIDE + c4 * 4);
                *(float4*)(obase + 4 * j) = v;
            }
        }
    }
}

extern "C" void kernel_launch(void* const* d_in, const int* in_sizes, int n_in,
                              void* d_out, int out_size, void* d_ws, size_t ws_size,
                              hipStream_t stream) {
    const float* x    = (const float*)d_in[0];
    const float* minv = (const float*)d_in[1];
    const float* maxv = (const float*)d_in[2];
    const float* piv  = (const float*)d_in[3];
    const float* knnd = (const float*)d_in[4];
    const float* qm   = (const float*)d_in[5];
    const float* qs   = (const float*)d_in[6];
    const float* km   = (const float*)d_in[7];
    const float* ks   = (const float*)d_in[8];
    const float* W1   = (const float*)d_in[9];
    const float* b1   = (const float*)d_in[10];
    const float* W2   = (const float*)d_in[11];
    const float* b2   = (const float*)d_in[12];
    const float* W3   = (const float*)d_in[13];
    const float* b3   = (const float*)d_in[14];
    const float* W4   = (const float*)d_in[15];
    const float* b4   = (const float*)d_in[16];
    float* out = (float*)d_out;
    unsigned short* wsw = (unsigned short*)d_ws;   // needs 1,310,720 B

    conv_weights<<<2560, 256, 0, stream>>>(W1, W2, W3, W4, wsw);
    pivnet_fused<<<NROWS_TOTAL / MROWS, NTHREADS, 0, stream>>>(
        x, minv, maxv, piv, knnd, qm, qs, km, ks,
        wsw, b1, b2, b3, b4, out);
}